// Round 1
// baseline (4328.857 us; speedup 1.0000x reference)
//
#include <hip/hip_runtime.h>
#include <stdint.h>

#define NV 20000
#define NE 100000
#define NK 8
#define FIN 1024
#define FOUT 512
#define CFEAT 96
#define FTOT 1120
#define CAP 4096
#define ROUNDS 13

typedef unsigned int u32;
typedef unsigned long long u64;

// float -> order-preserving unsigned bits, and inverse
__device__ __forceinline__ u32 sb(float x) {
    u32 u = __float_as_uint(x);
    return u ^ ((u & 0x80000000u) ? 0xFFFFFFFFu : 0x80000000u);
}
__device__ __forceinline__ float isb(u32 s) {
    u32 u = (s & 0x80000000u) ? (s ^ 0x80000000u) : ~s;
    return __uint_as_float(u);
}

// ---------------- GEMM1: f[k][v] = x[v] . filt_w[k] + filt_b[k] ----------------
__global__ void k_f(const float* __restrict__ x, const float* __restrict__ fw,
                    const float* __restrict__ fb, float* __restrict__ f) {
    __shared__ float w[NK * FIN];  // 32 KB
    for (int i = threadIdx.x; i < NK * FIN; i += 256) w[i] = fw[i];
    __syncthreads();
    int wave = threadIdx.x >> 6, lane = threadIdx.x & 63;
    int v = blockIdx.x * 4 + wave;  // grid 5000 * 4 waves = 20000 exact
    float acc[NK];
#pragma unroll
    for (int k = 0; k < NK; k++) acc[k] = 0.f;
    const float* xr = x + (size_t)v * FIN;
    for (int c = 0; c < FIN / 64; c++) {
        int i = c * 64 + lane;
        float xv = xr[i];
#pragma unroll
        for (int k = 0; k < NK; k++) acc[k] = fmaf(xv, w[k * FIN + i], acc[k]);
    }
#pragma unroll
    for (int off = 32; off >= 1; off >>= 1)
#pragma unroll
        for (int k = 0; k < NK; k++) acc[k] += __shfl_xor(acc[k], off, 64);
    if (lane < NK) f[lane * NV + v] = acc[lane] + fb[lane];
}

__global__ void k_zero(u32* nmin, u32* mstcnt) {
    int t = threadIdx.x;
    if (t < NK) { nmin[t] = 0; mstcnt[t] = 0; }
}

// ---------------- descent pointers ----------------
__global__ void k_initdesc(const float* __restrict__ f, u64* __restrict__ cd) {
    int t = blockIdx.x * 256 + threadIdx.x;  // 160000
    u32 v = (u32)(t % NV);
    cd[t] = ((u64)sb(f[t]) << 32) | v;
}

__global__ void k_descedge(const int* __restrict__ ei, const float* __restrict__ f,
                           u64* __restrict__ cd) {
    int t = blockIdx.x * 256 + threadIdx.x;  // 800000
    int k = t / NE, e = t % NE;
    int a = ei[e], b = ei[NE + e];
    if (a == b) return;
    float fa = f[k * NV + a], fb2 = f[k * NV + b];
    int d, l; float fl;
    if (fa >= fb2) { d = a; l = b; fl = fb2; } else { d = b; l = a; fl = fa; }
    u64 key = ((u64)sb(fl) << 32) | (u32)l;
    atomicMin(&cd[k * NV + d], key);
}

__global__ void k_basin(const u64* __restrict__ cd, u32* __restrict__ basin) {
    int t = blockIdx.x * 256 + threadIdx.x;
    int k = t / NV;
    u32 m = (u32)(t % NV);
    const u64* c = cd + (size_t)k * NV;
    while (true) { u32 n = (u32)c[m]; if (n == m) break; m = n; }
    basin[t] = m;
}

__global__ void k_minima(const u64* __restrict__ cd, u32* nmin,
                         u32* __restrict__ mlist, u32* __restrict__ dense) {
    int t = blockIdx.x * 256 + threadIdx.x;
    int k = t / NV; u32 v = (u32)(t % NV);
    if ((u32)cd[t] == v) {
        u32 i = atomicAdd(&nmin[k], 1u);
        if (i < CAP) { mlist[k * CAP + i] = v; dense[t] = i; }
    }
}

__global__ void k_edgeprep(const int* __restrict__ ei, const float* __restrict__ f,
                           const u32* __restrict__ basin, const u32* __restrict__ dense,
                           u64* __restrict__ wkey, u32* __restrict__ ep) {
    int t = blockIdx.x * 256 + threadIdx.x;  // 800000
    int k = t / NE, e = t % NE;
    int a = ei[e], b = ei[NE + e];
    if (a == b) { ep[t] = 0xFFFFFFFFu; return; }
    float fa = f[k * NV + a], fb2 = f[k * NV + b];
    float w = (fa >= fb2) ? fa : fb2;
    wkey[t] = ((u64)sb(w) << 32) | (u32)e;
    u32 ba = basin[k * NV + a], bb = basin[k * NV + b];
    if (ba == bb) { ep[t] = 0xFFFFFFFFu; return; }
    u32 da = dense[k * NV + ba], db = dense[k * NV + bb];
    ep[t] = (da << 16) | db;
}

// ---------------- Boruvka MSF on reduced minima graph ----------------
__device__ __forceinline__ u32 rootof(const u32* __restrict__ comp, u32 i) {
    while (true) { u32 p = comp[i]; if (p == i) return i; i = p; }
}

__global__ void k_binit(u32* __restrict__ comp) {
    int t = blockIdx.x * 256 + threadIdx.x;  // 32768
    comp[t] = (u32)(t % CAP);
}

__global__ void k_clear(u64* __restrict__ cand) {
    int t = blockIdx.x * 256 + threadIdx.x;
    cand[t] = ~0ull;
}

__global__ void k_edgemin(const u32* __restrict__ ep, const u64* __restrict__ wkey,
                          const u32* __restrict__ comp, u64* __restrict__ cand) {
    int t = blockIdx.x * 256 + threadIdx.x;  // 800000
    u32 p32 = ep[t];
    if (p32 == 0xFFFFFFFFu) return;
    int k = t / NE;
    const u32* c = comp + k * CAP;
    u32 A = rootof(c, p32 >> 16), B = rootof(c, p32 & 0xFFFFu);
    if (A == B) return;
    u64 w = wkey[t];
    u64* cnd = cand + k * CAP;
    atomicMin(&cnd[A], w);
    atomicMin(&cnd[B], w);
}

__global__ void k_hook(const u64* __restrict__ cand, const u32* __restrict__ ep,
                       const u32* __restrict__ comp, u32* __restrict__ hk) {
    int t = blockIdx.x * 256 + threadIdx.x;  // 32768
    int k = t / CAP; u32 i = (u32)(t % CAP);
    u64 cc = cand[t];
    if (cc == ~0ull) { hk[t] = i; return; }
    u32 e = (u32)cc;
    u32 p32 = ep[(size_t)k * NE + e];
    const u32* c = comp + k * CAP;
    u32 A = rootof(c, p32 >> 16), B = rootof(c, p32 & 0xFFFFu);
    hk[t] = (A == i) ? B : A;
}

__global__ void k_apply(const u64* __restrict__ cand, const u32* __restrict__ ep,
                        u32* __restrict__ comp, const u32* __restrict__ hk,
                        u32* mstcnt, u64* __restrict__ mkey, u32* __restrict__ mpay) {
    int t = blockIdx.x * 256 + threadIdx.x;  // 32768
    int k = t / CAP; u32 i = (u32)(t % CAP);
    u32 o = hk[t];
    if (o == i) return;
    bool mutual = (hk[k * CAP + o] == i);
    if (mutual && i < o) return;  // star center stays root; other side appends
    comp[t] = o;
    u64 cc = cand[t];
    u32 e = (u32)cc;
    u32 j = atomicAdd(&mstcnt[k], 1u);
    if (j < CAP) { mkey[k * CAP + j] = cc; mpay[k * CAP + j] = ep[(size_t)k * NE + e]; }
}

__global__ void k_compress(u32* __restrict__ comp) {
    int t = blockIdx.x * 256 + threadIdx.x;
    int k = t / CAP; u32 i = (u32)(t % CAP);
    u32* c = comp + k * CAP;
    c[i] = rootof(c, i);
}

// ---------------- sort MSF edges per filtration (bitonic in LDS) ----------------
__global__ void k_sort(const u32* mstcnt, u64* __restrict__ mkey, u32* __restrict__ mpay) {
    __shared__ u64 skey[CAP];   // 32 KB
    __shared__ u32 spay[CAP];   // 16 KB
    int k = blockIdx.x;
    u32 cnt = mstcnt[k]; if (cnt > CAP) cnt = CAP;
    for (int i = threadIdx.x; i < CAP; i += 256) {
        skey[i] = (i < (int)cnt) ? mkey[k * CAP + i] : ~0ull;
        spay[i] = (i < (int)cnt) ? mpay[k * CAP + i] : 0u;
    }
    __syncthreads();
    for (int sz = 2; sz <= CAP; sz <<= 1) {
        for (int st = sz >> 1; st >= 1; st >>= 1) {
            for (int i = threadIdx.x; i < CAP; i += 256) {
                int j = i ^ st;
                if (j > i) {
                    bool up = ((i & sz) == 0);
                    u64 a = skey[i], b = skey[j];
                    bool sw = up ? (a > b) : (a < b);
                    if (sw) {
                        skey[i] = b; skey[j] = a;
                        u32 tp = spay[i]; spay[i] = spay[j]; spay[j] = tp;
                    }
                }
            }
            __syncthreads();
        }
    }
    for (int i = threadIdx.x; i < CAP; i += 256) {
        mkey[k * CAP + i] = skey[i];
        mpay[k * CAP + i] = spay[i];
    }
}

// ---------------- elder-rule pairing (serial Kruskal over sorted MSF, in LDS) ----------------
__device__ __forceinline__ u32 findp(u64* pf, u32 x) {
    u32 p = (u32)pf[x];
    while (p != x) {
        u32 g = (u32)pf[p];
        pf[x] = (pf[x] & 0xFFFFFFFF00000000ull) | g;  // path halving
        x = g;
        p = (u32)pf[x];
    }
    return x;
}

__global__ void k_pair(const u32* nmin, const u32* __restrict__ mlist, const u32* mstcnt,
                       const u64* __restrict__ mkey, const u32* __restrict__ mpay,
                       const float* __restrict__ f, float* __restrict__ dval) {
    __shared__ u64 pf[CAP];    // low32 = parent (dense id), high32 = root's f bits
    __shared__ float dv[CAP];
    int k = blockIdx.x;
    u32 nm = nmin[k]; if (nm > CAP) nm = CAP;
    // default: death value = birth value (non-minima and essential minima)
    for (int v = threadIdx.x; v < NV; v += 256) dval[k * NV + v] = f[k * NV + v];
    for (int i = threadIdx.x; i < CAP; i += 256) {
        float fm = 0.f;
        if (i < (int)nm) fm = f[k * NV + mlist[k * CAP + i]];
        pf[i] = ((u64)__float_as_uint(fm) << 32) | (u32)i;
    }
    __syncthreads();
    if (threadIdx.x == 0) {
        u32 cnt = mstcnt[k]; if (cnt > CAP) cnt = CAP;
        for (u32 j = 0; j < cnt; j++) {
            u64 key = mkey[k * CAP + j];
            if (key == ~0ull) break;
            u32 pay = mpay[k * CAP + j];
            u32 A = findp(pf, pay >> 16);
            u32 B = findp(pf, pay & 0xFFFFu);
            if (A == B) continue;
            float fA = __uint_as_float((u32)(pf[A] >> 32));
            float fB = __uint_as_float((u32)(pf[B] >> 32));
            u32 old_, yg;
            if (fA <= fB) { old_ = A; yg = B; } else { old_ = B; yg = A; }
            dv[yg] = isb((u32)(key >> 32));
            pf[yg] = (pf[yg] & 0xFFFFFFFF00000000ull) | old_;
        }
    }
    __syncthreads();
    for (int i = threadIdx.x; i < CAP; i += 256) {
        if (i < (int)nm && (u32)pf[i] != (u32)i)
            dval[k * NV + mlist[k * CAP + i]] = dv[i];
    }
}

// ---------------- coordinate features ----------------
__global__ void k_coord(const float* __restrict__ f, const float* __restrict__ dval,
                        const float* __restrict__ tri_t, const float* __restrict__ gmu,
                        const float* __restrict__ gsig, const float* __restrict__ lw,
                        const float* __restrict__ rc, const float* __restrict__ rr,
                        float* __restrict__ coord) {
    int t = blockIdx.x * 256 + threadIdx.x;  // 160000
    int k = t / NV, v = t % NV;
    float b = f[t], d = dval[t];
    float* o = coord + (size_t)v * CFEAT + k * 12;
    float s = gsig[0];
    float inv2s2 = 1.0f / (2.0f * s * s);
    float r = fabsf(rr[0]);
#pragma unroll
    for (int j = 0; j < 3; j++) {
        float tri = d - fabsf(tri_t[j] - b);
        o[j] = tri > 0.f ? tri : 0.f;
        float dx = b - gmu[2 * j], dy = d - gmu[2 * j + 1];
        o[3 + j] = expf(-(dx * dx + dy * dy) * inv2s2);
        o[6 + j] = b * lw[2 * j] + d * lw[2 * j + 1];
        float q = fabsf(b - rc[2 * j]) + fabsf(d - rc[2 * j + 1]);
        o[9 + j] = 1.0f / (1.0f + q) - 1.0f / (1.0f + fabsf(r - q));
    }
}

// ---------------- GEMM2: out = [x | coord] @ out_w^T + out_b ----------------
__global__ void k_gemm(const float* __restrict__ x, const float* __restrict__ coord,
                       const float* __restrict__ w, const float* __restrict__ bias,
                       float* __restrict__ out) {
    __shared__ float As[64][17];
    __shared__ float Bs[64][17];
    int tx = threadIdx.x % 16, ty = threadIdx.x / 16;
    int v0 = blockIdx.y * 64, o0 = blockIdx.x * 64;
    float C[4][4] = {};
    for (int kk = 0; kk < FTOT; kk += 16) {
        for (int l = threadIdx.x; l < 64 * 16; l += 256) {
            int r = l / 16, c = l % 16;
            int vv = v0 + r, col = kk + c;
            float va = 0.f;
            if (vv < NV)
                va = (col < FIN) ? x[(size_t)vv * FIN + col]
                                 : coord[(size_t)vv * CFEAT + (col - FIN)];
            As[r][c] = va;
            Bs[r][c] = w[(size_t)(o0 + r) * FTOT + col];
        }
        __syncthreads();
#pragma unroll
        for (int tt = 0; tt < 16; tt++) {
            float av[4], bv[4];
#pragma unroll
            for (int i2 = 0; i2 < 4; i2++) av[i2] = As[ty * 4 + i2][tt];
#pragma unroll
            for (int j2 = 0; j2 < 4; j2++) bv[j2] = Bs[tx * 4 + j2][tt];
#pragma unroll
            for (int i2 = 0; i2 < 4; i2++)
#pragma unroll
                for (int j2 = 0; j2 < 4; j2++)
                    C[i2][j2] = fmaf(av[i2], bv[j2], C[i2][j2]);
        }
        __syncthreads();
    }
#pragma unroll
    for (int i2 = 0; i2 < 4; i2++) {
        int vv = v0 + ty * 4 + i2;
        if (vv >= NV) continue;
#pragma unroll
        for (int j2 = 0; j2 < 4; j2++) {
            int oo = o0 + tx * 4 + j2;
            out[(size_t)vv * FOUT + oo] = C[i2][j2] + bias[oo];
        }
    }
}

extern "C" void kernel_launch(void* const* d_in, const int* in_sizes, int n_in,
                              void* d_out, int out_size, void* d_ws, size_t ws_size,
                              hipStream_t stream) {
    const float* x     = (const float*)d_in[0];
    const int*   ei    = (const int*)d_in[1];
    const float* fw    = (const float*)d_in[2];
    const float* fbv   = (const float*)d_in[3];
    const float* tri_t = (const float*)d_in[4];
    const float* gmu   = (const float*)d_in[5];
    const float* gsig  = (const float*)d_in[6];
    const float* lw    = (const float*)d_in[7];
    const float* rc    = (const float*)d_in[8];
    const float* rr    = (const float*)d_in[9];
    const float* ow    = (const float*)d_in[10];
    const float* ob    = (const float*)d_in[11];
    float* out = (float*)d_out;

    char* p = (char*)d_ws;
    auto alloc = [&](size_t bytes) -> void* {
        void* q = (void*)p;
        p += (bytes + 255) & ~(size_t)255;
        return q;
    };
    float* f     = (float*)alloc((size_t)NK * NV * 4);
    u64*   cd    = (u64*)  alloc((size_t)NK * NV * 8);
    u32*   basin = (u32*)  alloc((size_t)NK * NV * 4);
    u32*   dense = (u32*)  alloc((size_t)NK * NV * 4);
    u32*   mlist = (u32*)  alloc((size_t)NK * CAP * 4);
    u32*   cnts  = (u32*)  alloc(64 * 4);
    u64*   wkey  = (u64*)  alloc((size_t)NK * NE * 8);
    u32*   ep    = (u32*)  alloc((size_t)NK * NE * 4);
    u32*   comp  = (u32*)  alloc((size_t)NK * CAP * 4);
    u64*   cand  = (u64*)  alloc((size_t)NK * CAP * 8);
    u32*   hk    = (u32*)  alloc((size_t)NK * CAP * 4);
    u64*   mkey  = (u64*)  alloc((size_t)NK * CAP * 8);
    u32*   mpay  = (u32*)  alloc((size_t)NK * CAP * 4);
    float* dval  = (float*)alloc((size_t)NK * NV * 4);
    float* coord = (float*)alloc((size_t)NV * CFEAT * 4);
    u32* nmin = cnts; u32* mstcnt = cnts + 8;

    k_zero<<<1, 64, 0, stream>>>(nmin, mstcnt);
    k_f<<<5000, 256, 0, stream>>>(x, fw, fbv, f);
    k_initdesc<<<625, 256, 0, stream>>>(f, cd);
    k_descedge<<<3125, 256, 0, stream>>>(ei, f, cd);
    k_basin<<<625, 256, 0, stream>>>(cd, basin);
    k_minima<<<625, 256, 0, stream>>>(cd, nmin, mlist, dense);
    k_edgeprep<<<3125, 256, 0, stream>>>(ei, f, basin, dense, wkey, ep);
    k_binit<<<128, 256, 0, stream>>>(comp);
    for (int r = 0; r < ROUNDS; r++) {
        k_clear<<<128, 256, 0, stream>>>(cand);
        k_edgemin<<<3125, 256, 0, stream>>>(ep, wkey, comp, cand);
        k_hook<<<128, 256, 0, stream>>>(cand, ep, comp, hk);
        k_apply<<<128, 256, 0, stream>>>(cand, ep, comp, hk, mstcnt, mkey, mpay);
        k_compress<<<128, 256, 0, stream>>>(comp);
    }
    k_sort<<<8, 256, 0, stream>>>(mstcnt, mkey, mpay);
    k_pair<<<8, 256, 0, stream>>>(nmin, mlist, mstcnt, mkey, mpay, f, dval);
    k_coord<<<625, 256, 0, stream>>>(f, dval, tri_t, gmu, gsig, lw, rc, rr, coord);
    k_gemm<<<dim3(8, 313), 256, 0, stream>>>(x, coord, ow, ob, out);
}

// Round 2
// 1917.983 us; speedup vs baseline: 2.2570x; 2.2570x over previous
//
#include <hip/hip_runtime.h>
#include <stdint.h>

#define NV 20000
#define NE 100000
#define NK 8
#define FIN 1024
#define FOUT 512
#define CFEAT 96
#define FTOT 1120
#define CAP 4096
#define ROUNDS 13
#define NB 16          // edge-chunk blocks per filtration in k_candA
#define CHUNK (NE / NB)

typedef unsigned int u32;
typedef unsigned long long u64;

// float -> order-preserving unsigned bits, and inverse
__device__ __forceinline__ u32 sb(float x) {
    u32 u = __float_as_uint(x);
    return u ^ ((u & 0x80000000u) ? 0xFFFFFFFFu : 0x80000000u);
}
__device__ __forceinline__ float isb(u32 s) {
    u32 u = (s & 0x80000000u) ? (s ^ 0x80000000u) : ~s;
    return __uint_as_float(u);
}

// ---------------- GEMM1: f[k][v] = x[v] . filt_w[k] + filt_b[k] ----------------
__global__ void k_f(const float* __restrict__ x, const float* __restrict__ fw,
                    const float* __restrict__ fb, float* __restrict__ f) {
    __shared__ float w[NK * FIN];  // 32 KB
    for (int i = threadIdx.x; i < NK * FIN; i += 256) w[i] = fw[i];
    __syncthreads();
    int wave = threadIdx.x >> 6, lane = threadIdx.x & 63;
    int v = blockIdx.x * 4 + wave;  // 5000 * 4 waves = 20000 exact
    float acc[NK];
#pragma unroll
    for (int k = 0; k < NK; k++) acc[k] = 0.f;
    const float* xr = x + (size_t)v * FIN;
    for (int c = 0; c < FIN / 64; c++) {
        int i = c * 64 + lane;
        float xv = xr[i];
#pragma unroll
        for (int k = 0; k < NK; k++) acc[k] = fmaf(xv, w[k * FIN + i], acc[k]);
    }
#pragma unroll
    for (int off = 32; off >= 1; off >>= 1)
#pragma unroll
        for (int k = 0; k < NK; k++) acc[k] += __shfl_xor(acc[k], off, 64);
    if (lane < NK) f[lane * NV + v] = acc[lane] + fb[lane];
}

// ---------------- init: comp identity, cand = ~0, counters = 0 ----------------
__global__ void k_init(u32* __restrict__ comp, u64* __restrict__ cand, u32* cnts) {
    int t = blockIdx.x * 256 + threadIdx.x;  // 32768
    comp[t] = (u32)(t % CAP);
    cand[t] = ~0ull;
    if (t < 16) cnts[t] = 0;
}

// ---------------- descent pointers ----------------
__global__ void k_initdesc(const float* __restrict__ f, u64* __restrict__ cd) {
    int t = blockIdx.x * 256 + threadIdx.x;  // 160000
    u32 v = (u32)(t % NV);
    cd[t] = ((u64)sb(f[t]) << 32) | v;
}

__global__ void k_descedge(const int* __restrict__ ei, const float* __restrict__ f,
                           u64* __restrict__ cd) {
    int t = blockIdx.x * 256 + threadIdx.x;  // 800000
    int k = t / NE, e = t % NE;
    int a = ei[e], b = ei[NE + e];
    if (a == b) return;
    float fa = f[k * NV + a], fb2 = f[k * NV + b];
    int d, l; float fl;
    if (fa >= fb2) { d = a; l = b; fl = fb2; } else { d = b; l = a; fl = fa; }
    u64 key = ((u64)sb(fl) << 32) | (u32)l;
    atomicMin(&cd[k * NV + d], key);
}

__global__ void k_basin(const u64* __restrict__ cd, u32* __restrict__ basin) {
    int t = blockIdx.x * 256 + threadIdx.x;
    int k = t / NV;
    u32 m = (u32)(t % NV);
    const u64* c = cd + (size_t)k * NV;
    while (true) { u32 n = (u32)c[m]; if (n == m) break; m = n; }
    basin[t] = m;
}

__global__ void k_minima(const u64* __restrict__ cd, u32* nmin,
                         u32* __restrict__ mlist, u32* __restrict__ dense) {
    int t = blockIdx.x * 256 + threadIdx.x;
    int k = t / NV; u32 v = (u32)(t % NV);
    if ((u32)cd[t] == v) {
        u32 i = atomicAdd(&nmin[k], 1u);
        if (i < CAP) { mlist[k * CAP + i] = v; dense[t] = i; }
    }
}

__global__ void k_edgeprep(const int* __restrict__ ei, const float* __restrict__ f,
                           const u32* __restrict__ basin, const u32* __restrict__ dense,
                           u64* __restrict__ wkey, u32* __restrict__ ep) {
    int t = blockIdx.x * 256 + threadIdx.x;  // 800000
    int k = t / NE, e = t % NE;
    int a = ei[e], b = ei[NE + e];
    if (a == b) { ep[t] = 0xFFFFFFFFu; return; }
    float fa = f[k * NV + a], fb2 = f[k * NV + b];
    float w = (fa >= fb2) ? fa : fb2;
    wkey[t] = ((u64)sb(w) << 32) | (u32)e;
    u32 ba = basin[k * NV + a], bb = basin[k * NV + b];
    if (ba == bb) { ep[t] = 0xFFFFFFFFu; return; }
    u32 da = dense[k * NV + ba], db = dense[k * NV + bb];
    ep[t] = (da << 16) | db;
}

// ---------------- Boruvka phase A: per-block LDS cand, sparse flush ----------------
__device__ __forceinline__ u32 rootofs(const u32* c, u32 i) {
    while (true) { u32 p = c[i]; if (p == i) return i; i = p; }
}

__global__ void k_candA(const u32* __restrict__ ep, const u64* __restrict__ wkey,
                        const u32* __restrict__ comp_g, u64* __restrict__ cand_g) {
    __shared__ u32 scomp[CAP];  // 16 KB
    __shared__ u64 scand[CAP];  // 32 KB
    int k = blockIdx.y, b = blockIdx.x;
    for (int i = threadIdx.x; i < CAP; i += 256) {
        scomp[i] = comp_g[k * CAP + i];
        scand[i] = ~0ull;
    }
    __syncthreads();
    int e0 = b * CHUNK;
    const u32* epk = ep + (size_t)k * NE;
    const u64* wkk = wkey + (size_t)k * NE;
    for (int e = e0 + threadIdx.x; e < e0 + CHUNK; e += 256) {
        u32 p32 = epk[e];
        if (p32 == 0xFFFFFFFFu) continue;
        u32 A = rootofs(scomp, p32 >> 16), B = rootofs(scomp, p32 & 0xFFFFu);
        if (A == B) continue;
        u64 w = wkk[e];
        atomicMin(&scand[A], w);
        atomicMin(&scand[B], w);
    }
    __syncthreads();
    u64* cnd = cand_g + (size_t)k * CAP;
    for (int i = threadIdx.x; i < CAP; i += 256) {
        u64 v = scand[i];
        if (v != ~0ull) atomicMin(&cnd[i], v);
    }
}

// ---------------- Boruvka phase B: hook + apply + compress + clear (fused) ------
__global__ void k_round(u64* __restrict__ cand_g, const u32* __restrict__ ep,
                        u32* __restrict__ comp_g, u32* mstcnt,
                        u64* __restrict__ mkey, u32* __restrict__ mpay) {
    __shared__ u64 scand[CAP];  // 32 KB
    __shared__ u32 scomp[CAP];  // 16 KB
    __shared__ u32 shk[CAP];    // 16 KB
    int k = blockIdx.x;
    for (int i = threadIdx.x; i < CAP; i += 1024) {
        scand[i] = cand_g[k * CAP + i];
        scomp[i] = comp_g[k * CAP + i];
    }
    __syncthreads();
    // hook
    for (int i = threadIdx.x; i < CAP; i += 1024) {
        u64 cc = scand[i];
        if (cc == ~0ull) { shk[i] = (u32)i; continue; }
        u32 e = (u32)cc;
        u32 p32 = ep[(size_t)k * NE + e];
        u32 A = rootofs(scomp, p32 >> 16), B = rootofs(scomp, p32 & 0xFFFFu);
        shk[i] = (A == (u32)i) ? B : A;
    }
    __syncthreads();
    // apply (star-center stays root on mutual hooks)
    for (int i = threadIdx.x; i < CAP; i += 1024) {
        u32 o = shk[i];
        if (o == (u32)i) continue;
        bool mutual = (shk[o] == (u32)i);
        if (mutual && (u32)i < o) continue;
        scomp[i] = o;
        u64 cc = scand[i];
        u32 e = (u32)cc;
        u32 j = atomicAdd(&mstcnt[k], 1u);
        if (j < CAP) { mkey[k * CAP + j] = cc; mpay[k * CAP + j] = ep[(size_t)k * NE + e]; }
    }
    __syncthreads();
    // compress
    for (int i = threadIdx.x; i < CAP; i += 1024) scomp[i] = rootofs(scomp, i);
    __syncthreads();
    for (int i = threadIdx.x; i < CAP; i += 1024) {
        comp_g[k * CAP + i] = scomp[i];
        cand_g[k * CAP + i] = ~0ull;  // cleared for next round
    }
}

// ---------------- sort MSF edges per filtration (bitonic in LDS) ----------------
__global__ void k_sort(const u32* mstcnt, u64* __restrict__ mkey, u32* __restrict__ mpay) {
    __shared__ u64 skey[CAP];   // 32 KB
    __shared__ u32 spay[CAP];   // 16 KB
    int k = blockIdx.x;
    u32 cnt = mstcnt[k]; if (cnt > CAP) cnt = CAP;
    for (int i = threadIdx.x; i < CAP; i += 256) {
        skey[i] = (i < (int)cnt) ? mkey[k * CAP + i] : ~0ull;
        spay[i] = (i < (int)cnt) ? mpay[k * CAP + i] : 0u;
    }
    __syncthreads();
    for (int sz = 2; sz <= CAP; sz <<= 1) {
        for (int st = sz >> 1; st >= 1; st >>= 1) {
            for (int i = threadIdx.x; i < CAP; i += 256) {
                int j = i ^ st;
                if (j > i) {
                    bool up = ((i & sz) == 0);
                    u64 a = skey[i], b = skey[j];
                    bool sw = up ? (a > b) : (a < b);
                    if (sw) {
                        skey[i] = b; skey[j] = a;
                        u32 tp = spay[i]; spay[i] = spay[j]; spay[j] = tp;
                    }
                }
            }
            __syncthreads();
        }
    }
    for (int i = threadIdx.x; i < CAP; i += 256) {
        mkey[k * CAP + i] = skey[i];
        mpay[k * CAP + i] = spay[i];
    }
}

// ---------------- elder-rule pairing (serial Kruskal over sorted MSF, in LDS) ----
// pf[i]: low32 = parent (dense id); high32 = root's f bits while root,
//        repurposed as death-value sortbits once i is merged (never a root again).
__device__ __forceinline__ u32 findp(u64* pf, u32 x) {
    u32 p = (u32)pf[x];
    while (p != x) {
        u32 g = (u32)pf[p];
        pf[x] = (pf[x] & 0xFFFFFFFF00000000ull) | g;  // path halving
        x = g;
        p = (u32)pf[x];
    }
    return x;
}

__global__ void k_pair(const u32* nmin, const u32* __restrict__ mlist, const u32* mstcnt,
                       const u64* __restrict__ mkey, const u32* __restrict__ mpay,
                       const float* __restrict__ f, float* __restrict__ dval) {
    __shared__ u64 pf[CAP];    // 32 KB
    __shared__ u32 skey[CAP];  // 16 KB: weight sortbits of sorted MSF edges
    __shared__ u32 spay[CAP];  // 16 KB: dense endpoint pair
    int k = blockIdx.x;
    u32 nm = nmin[k]; if (nm > CAP) nm = CAP;
    u32 cnt = mstcnt[k]; if (cnt > CAP) cnt = CAP;
    // default: death value = birth value (non-minima and essential minima)
    for (int v = threadIdx.x; v < NV; v += 512) dval[k * NV + v] = f[k * NV + v];
    for (int i = threadIdx.x; i < CAP; i += 512) {
        float fm = 0.f;
        if (i < (int)nm) fm = f[k * NV + mlist[k * CAP + i]];
        pf[i] = ((u64)__float_as_uint(fm) << 32) | (u32)i;
        skey[i] = (u32)(mkey[k * CAP + i] >> 32);
        spay[i] = mpay[k * CAP + i];
    }
    __syncthreads();
    if (threadIdx.x == 0) {
        u32 wb = skey[0], pp = spay[0];
        for (u32 j = 0; j < cnt; j++) {
            u32 jn = (j + 1 < cnt) ? j + 1 : 0;
            u32 wb2 = skey[jn], pp2 = spay[jn];  // prefetch
            u32 A = findp(pf, pp >> 16);
            u32 B = findp(pf, pp & 0xFFFFu);
            if (A != B) {
                float fA = __uint_as_float((u32)(pf[A] >> 32));
                float fB = __uint_as_float((u32)(pf[B] >> 32));
                u32 old_, yg;
                if (fA <= fB) { old_ = A; yg = B; } else { old_ = B; yg = A; }
                pf[yg] = ((u64)wb << 32) | old_;  // high32 := death sortbits
            }
            wb = wb2; pp = pp2;
        }
    }
    __syncthreads();
    for (int i = threadIdx.x; i < (int)nm; i += 512) {
        if ((u32)pf[i] != (u32)i)
            dval[k * NV + mlist[k * CAP + i]] = isb((u32)(pf[i] >> 32));
    }
}

// ---------------- coordinate features ----------------
__global__ void k_coord(const float* __restrict__ f, const float* __restrict__ dval,
                        const float* __restrict__ tri_t, const float* __restrict__ gmu,
                        const float* __restrict__ gsig, const float* __restrict__ lw,
                        const float* __restrict__ rc, const float* __restrict__ rr,
                        float* __restrict__ coord) {
    int t = blockIdx.x * 256 + threadIdx.x;  // 160000
    int k = t / NV, v = t % NV;
    float b = f[t], d = dval[t];
    float* o = coord + (size_t)v * CFEAT + k * 12;
    float s = gsig[0];
    float inv2s2 = 1.0f / (2.0f * s * s);
    float r = fabsf(rr[0]);
#pragma unroll
    for (int j = 0; j < 3; j++) {
        float tri = d - fabsf(tri_t[j] - b);
        o[j] = tri > 0.f ? tri : 0.f;
        float dx = b - gmu[2 * j], dy = d - gmu[2 * j + 1];
        o[3 + j] = expf(-(dx * dx + dy * dy) * inv2s2);
        o[6 + j] = b * lw[2 * j] + d * lw[2 * j + 1];
        float q = fabsf(b - rc[2 * j]) + fabsf(d - rc[2 * j + 1]);
        o[9 + j] = 1.0f / (1.0f + q) - 1.0f / (1.0f + fabsf(r - q));
    }
}

// ---------------- GEMM2: out = [x | coord] @ out_w^T + out_b ----------------
__global__ void k_gemm(const float* __restrict__ x, const float* __restrict__ coord,
                       const float* __restrict__ w, const float* __restrict__ bias,
                       float* __restrict__ out) {
    __shared__ float As[64][17];
    __shared__ float Bs[64][17];
    int tx = threadIdx.x % 16, ty = threadIdx.x / 16;
    int v0 = blockIdx.y * 64, o0 = blockIdx.x * 64;
    float C[4][4] = {};
    for (int kk = 0; kk < FTOT; kk += 16) {
        for (int l = threadIdx.x; l < 64 * 16; l += 256) {
            int r = l / 16, c = l % 16;
            int vv = v0 + r, col = kk + c;
            float va = 0.f;
            if (vv < NV)
                va = (col < FIN) ? x[(size_t)vv * FIN + col]
                                 : coord[(size_t)vv * CFEAT + (col - FIN)];
            As[r][c] = va;
            Bs[r][c] = w[(size_t)(o0 + r) * FTOT + col];
        }
        __syncthreads();
#pragma unroll
        for (int tt = 0; tt < 16; tt++) {
            float av[4], bv[4];
#pragma unroll
            for (int i2 = 0; i2 < 4; i2++) av[i2] = As[ty * 4 + i2][tt];
#pragma unroll
            for (int j2 = 0; j2 < 4; j2++) bv[j2] = Bs[tx * 4 + j2][tt];
#pragma unroll
            for (int i2 = 0; i2 < 4; i2++)
#pragma unroll
                for (int j2 = 0; j2 < 4; j2++)
                    C[i2][j2] = fmaf(av[i2], bv[j2], C[i2][j2]);
        }
        __syncthreads();
    }
#pragma unroll
    for (int i2 = 0; i2 < 4; i2++) {
        int vv = v0 + ty * 4 + i2;
        if (vv >= NV) continue;
#pragma unroll
        for (int j2 = 0; j2 < 4; j2++) {
            int oo = o0 + tx * 4 + j2;
            out[(size_t)vv * FOUT + oo] = C[i2][j2] + bias[oo];
        }
    }
}

extern "C" void kernel_launch(void* const* d_in, const int* in_sizes, int n_in,
                              void* d_out, int out_size, void* d_ws, size_t ws_size,
                              hipStream_t stream) {
    const float* x     = (const float*)d_in[0];
    const int*   ei    = (const int*)d_in[1];
    const float* fw    = (const float*)d_in[2];
    const float* fbv   = (const float*)d_in[3];
    const float* tri_t = (const float*)d_in[4];
    const float* gmu   = (const float*)d_in[5];
    const float* gsig  = (const float*)d_in[6];
    const float* lw    = (const float*)d_in[7];
    const float* rc    = (const float*)d_in[8];
    const float* rr    = (const float*)d_in[9];
    const float* ow    = (const float*)d_in[10];
    const float* ob    = (const float*)d_in[11];
    float* out = (float*)d_out;

    char* p = (char*)d_ws;
    auto alloc = [&](size_t bytes) -> void* {
        void* q = (void*)p;
        p += (bytes + 255) & ~(size_t)255;
        return q;
    };
    float* f     = (float*)alloc((size_t)NK * NV * 4);
    u64*   cd    = (u64*)  alloc((size_t)NK * NV * 8);
    u32*   basin = (u32*)  alloc((size_t)NK * NV * 4);
    u32*   dense = (u32*)  alloc((size_t)NK * NV * 4);
    u32*   mlist = (u32*)  alloc((size_t)NK * CAP * 4);
    u32*   cnts  = (u32*)  alloc(64 * 4);
    u64*   wkey  = (u64*)  alloc((size_t)NK * NE * 8);
    u32*   ep    = (u32*)  alloc((size_t)NK * NE * 4);
    u32*   comp  = (u32*)  alloc((size_t)NK * CAP * 4);
    u64*   cand  = (u64*)  alloc((size_t)NK * CAP * 8);
    u64*   mkey  = (u64*)  alloc((size_t)NK * CAP * 8);
    u32*   mpay  = (u32*)  alloc((size_t)NK * CAP * 4);
    float* dval  = (float*)alloc((size_t)NK * NV * 4);
    float* coord = (float*)alloc((size_t)NV * CFEAT * 4);
    u32* nmin = cnts; u32* mstcnt = cnts + 8;

    k_init<<<128, 256, 0, stream>>>(comp, cand, cnts);
    k_f<<<5000, 256, 0, stream>>>(x, fw, fbv, f);
    k_initdesc<<<625, 256, 0, stream>>>(f, cd);
    k_descedge<<<3125, 256, 0, stream>>>(ei, f, cd);
    k_basin<<<625, 256, 0, stream>>>(cd, basin);
    k_minima<<<625, 256, 0, stream>>>(cd, nmin, mlist, dense);
    k_edgeprep<<<3125, 256, 0, stream>>>(ei, f, basin, dense, wkey, ep);
    for (int r = 0; r < ROUNDS; r++) {
        k_candA<<<dim3(NB, NK), 256, 0, stream>>>(ep, wkey, comp, cand);
        k_round<<<NK, 1024, 0, stream>>>(cand, ep, comp, mstcnt, mkey, mpay);
    }
    k_sort<<<8, 256, 0, stream>>>(mstcnt, mkey, mpay);
    k_pair<<<8, 512, 0, stream>>>(nmin, mlist, mstcnt, mkey, mpay, f, dval);
    k_coord<<<625, 256, 0, stream>>>(f, dval, tri_t, gmu, gsig, lw, rc, rr, coord);
    k_gemm<<<dim3(8, 313), 256, 0, stream>>>(x, coord, ow, ob, out);
}

// Round 3
// 1474.095 us; speedup vs baseline: 2.9366x; 1.3011x over previous
//
#include <hip/hip_runtime.h>
#include <stdint.h>

#define NV 20000
#define NE 100000
#define NK 8
#define FIN 1024
#define FOUT 512
#define FTOT 1120
#define KP 1152           // K padded to 18*64
#define MP 20096          // M padded to 157*128
#define CAP 4096
#define ROUNDS 13
#define NB 32             // edge-chunk blocks per filtration in k_candA
#define CHUNK (NE / NB)
#define LDA 72            // LDS row stride (bf16 elems): 64 + 8 pad

typedef unsigned int u32;
typedef unsigned long long u64;
typedef unsigned short u16;
typedef __attribute__((ext_vector_type(8))) short bf16x8;
typedef __attribute__((ext_vector_type(4))) float f32x4;

// float -> order-preserving unsigned bits, and inverse
__device__ __forceinline__ u32 sb(float x) {
    u32 u = __float_as_uint(x);
    return u ^ ((u & 0x80000000u) ? 0xFFFFFFFFu : 0x80000000u);
}
__device__ __forceinline__ float isb(u32 s) {
    u32 u = (s & 0x80000000u) ? (s ^ 0x80000000u) : ~s;
    return __uint_as_float(u);
}
// float -> bf16 (RNE)
__device__ __forceinline__ u16 f2bf(float f) {
    u32 u = __float_as_uint(f);
    return (u16)((u + 0x7FFFu + ((u >> 16) & 1u)) >> 16);
}

// ---------------- GEMM1: f[k][v] = x[v] . filt_w[k] + filt_b[k] (fp32 exact path)
__global__ void k_f(const float* __restrict__ x, const float* __restrict__ fw,
                    const float* __restrict__ fb, float* __restrict__ f) {
    __shared__ float w[NK * FIN];  // 32 KB
    for (int i = threadIdx.x; i < NK * FIN; i += 256) w[i] = fw[i];
    __syncthreads();
    int wave = threadIdx.x >> 6, lane = threadIdx.x & 63;
    int v = blockIdx.x * 4 + wave;  // 5000 * 4 waves = 20000 exact
    float acc[NK];
#pragma unroll
    for (int k = 0; k < NK; k++) acc[k] = 0.f;
    const float* xr = x + (size_t)v * FIN;
    for (int c = 0; c < FIN / 64; c++) {
        int i = c * 64 + lane;
        float xv = xr[i];
#pragma unroll
        for (int k = 0; k < NK; k++) acc[k] = fmaf(xv, w[k * FIN + i], acc[k]);
    }
#pragma unroll
    for (int off = 32; off >= 1; off >>= 1)
#pragma unroll
        for (int k = 0; k < NK; k++) acc[k] += __shfl_xor(acc[k], off, 64);
    if (lane < NK) f[lane * NV + v] = acc[lane] + fb[lane];
}

// ---------------- init: comp identity, cand = ~0, counters = 0 ----------------
__global__ void k_init(u32* __restrict__ comp, u64* __restrict__ cand, u32* cnts) {
    int t = blockIdx.x * 256 + threadIdx.x;  // 32768
    comp[t] = (u32)(t % CAP);
    cand[t] = ~0ull;
    if (t < 16) cnts[t] = 0;
}

// ---------------- cast x into fused bf16 A (cols 0..1023; zero pads) ----------
__global__ void k_castx(const float* __restrict__ x, u16* __restrict__ A) {
    int t = blockIdx.x * 256 + threadIdx.x;  // MP * 144
    if (t >= MP * 144) return;
    int v = t / 144, c = (t % 144) * 8;
    u32 pk[4];
    if (v < NV && c < FIN) {
        const float* xr = x + (size_t)v * FIN + c;
#pragma unroll
        for (int j = 0; j < 4; j++)
            pk[j] = (u32)f2bf(xr[2 * j]) | ((u32)f2bf(xr[2 * j + 1]) << 16);
    } else {
#pragma unroll
        for (int j = 0; j < 4; j++) pk[j] = 0u;
    }
    *(uint4*)(A + (size_t)v * KP + c) = make_uint4(pk[0], pk[1], pk[2], pk[3]);
}

// ---------------- cast out_w into bf16 W [512][1152] --------------------------
__global__ void k_castw(const float* __restrict__ ow, u16* __restrict__ W) {
    int t = blockIdx.x * 256 + threadIdx.x;  // 512*144
    if (t >= FOUT * 144) return;
    int n = t / 144, c = (t % 144) * 8;
    u32 pk[4];
    if (c < FTOT) {
        const float* wr = ow + (size_t)n * FTOT + c;
#pragma unroll
        for (int j = 0; j < 4; j++)
            pk[j] = (u32)f2bf(wr[2 * j]) | ((u32)f2bf(wr[2 * j + 1]) << 16);
    } else {
#pragma unroll
        for (int j = 0; j < 4; j++) pk[j] = 0u;
    }
    *(uint4*)(W + (size_t)n * KP + c) = make_uint4(pk[0], pk[1], pk[2], pk[3]);
}

// ---------------- descent pointers ----------------
__global__ void k_initdesc(const float* __restrict__ f, u64* __restrict__ cd) {
    int t = blockIdx.x * 256 + threadIdx.x;  // 160000
    u32 v = (u32)(t % NV);
    cd[t] = ((u64)sb(f[t]) << 32) | v;
}

__global__ void k_descedge(const int* __restrict__ ei, const float* __restrict__ f,
                           u64* __restrict__ cd) {
    int t = blockIdx.x * 256 + threadIdx.x;  // 800000
    int k = t / NE, e = t % NE;
    int a = ei[e], b = ei[NE + e];
    if (a == b) return;
    float fa = f[k * NV + a], fb2 = f[k * NV + b];
    int d, l; float fl;
    if (fa >= fb2) { d = a; l = b; fl = fb2; } else { d = b; l = a; fl = fa; }
    u64 key = ((u64)sb(fl) << 32) | (u32)l;
    atomicMin(&cd[k * NV + d], key);
}

__global__ void k_basin(const u64* __restrict__ cd, u32* __restrict__ basin) {
    int t = blockIdx.x * 256 + threadIdx.x;
    int k = t / NV;
    u32 m = (u32)(t % NV);
    const u64* c = cd + (size_t)k * NV;
    while (true) { u32 n = (u32)c[m]; if (n == m) break; m = n; }
    basin[t] = m;
}

__global__ void k_minima(const u64* __restrict__ cd, u32* nmin,
                         u32* __restrict__ mlist, u32* __restrict__ dense) {
    int t = blockIdx.x * 256 + threadIdx.x;
    int k = t / NV; u32 v = (u32)(t % NV);
    if ((u32)cd[t] == v) {
        u32 i = atomicAdd(&nmin[k], 1u);
        if (i < CAP) { mlist[k * CAP + i] = v; dense[t] = i; }
    }
}

__global__ void k_edgeprep(const int* __restrict__ ei, const float* __restrict__ f,
                           const u32* __restrict__ basin, const u32* __restrict__ dense,
                           u64* __restrict__ wkey, u32* __restrict__ ep) {
    int t = blockIdx.x * 256 + threadIdx.x;  // 800000
    int k = t / NE, e = t % NE;
    int a = ei[e], b = ei[NE + e];
    if (a == b) { ep[t] = 0xFFFFFFFFu; return; }
    float fa = f[k * NV + a], fb2 = f[k * NV + b];
    float w = (fa >= fb2) ? fa : fb2;
    wkey[t] = ((u64)sb(w) << 32) | (u32)e;
    u32 ba = basin[k * NV + a], bb = basin[k * NV + b];
    if (ba == bb) { ep[t] = 0xFFFFFFFFu; return; }
    u32 da = dense[k * NV + ba], db = dense[k * NV + bb];
    ep[t] = (da << 16) | db;
}

// ---------------- Boruvka phase A: per-block LDS cand, sparse flush ------------
__device__ __forceinline__ u32 rootofs(const u32* c, u32 i) {
    while (true) { u32 p = c[i]; if (p == i) return i; i = p; }
}

__global__ void k_candA(const u32* __restrict__ ep, const u64* __restrict__ wkey,
                        const u32* __restrict__ comp_g, u64* __restrict__ cand_g) {
    __shared__ u32 scomp[CAP];  // 16 KB
    __shared__ u64 scand[CAP];  // 32 KB
    int k = blockIdx.y, b = blockIdx.x;
    for (int i = threadIdx.x; i < CAP; i += 256) {
        scomp[i] = comp_g[k * CAP + i];
        scand[i] = ~0ull;
    }
    __syncthreads();
    int e0 = b * CHUNK;
    const u32* epk = ep + (size_t)k * NE;
    const u64* wkk = wkey + (size_t)k * NE;
    for (int e = e0 + threadIdx.x; e < e0 + CHUNK; e += 256) {
        u32 p32 = epk[e];
        if (p32 == 0xFFFFFFFFu) continue;
        u32 A = rootofs(scomp, p32 >> 16), B = rootofs(scomp, p32 & 0xFFFFu);
        if (A == B) continue;
        u64 w = wkk[e];
        atomicMin(&scand[A], w);
        atomicMin(&scand[B], w);
    }
    __syncthreads();
    u64* cnd = cand_g + (size_t)k * CAP;
    for (int i = threadIdx.x; i < CAP; i += 256) {
        u64 v = scand[i];
        if (v != ~0ull) atomicMin(&cnd[i], v);
    }
}

// ---------------- Boruvka phase B: hook + apply + compress + clear (fused) -----
__global__ void k_round(u64* __restrict__ cand_g, const u32* __restrict__ ep,
                        u32* __restrict__ comp_g, u32* mstcnt,
                        u64* __restrict__ mkey, u32* __restrict__ mpay) {
    __shared__ u64 scand[CAP];  // 32 KB
    __shared__ u32 scomp[CAP];  // 16 KB
    __shared__ u32 shk[CAP];    // 16 KB
    int k = blockIdx.x;
    for (int i = threadIdx.x; i < CAP; i += 1024) {
        scand[i] = cand_g[k * CAP + i];
        scomp[i] = comp_g[k * CAP + i];
    }
    __syncthreads();
    for (int i = threadIdx.x; i < CAP; i += 1024) {
        u64 cc = scand[i];
        if (cc == ~0ull) { shk[i] = (u32)i; continue; }
        u32 e = (u32)cc;
        u32 p32 = ep[(size_t)k * NE + e];
        u32 A = rootofs(scomp, p32 >> 16), B = rootofs(scomp, p32 & 0xFFFFu);
        shk[i] = (A == (u32)i) ? B : A;
    }
    __syncthreads();
    for (int i = threadIdx.x; i < CAP; i += 1024) {
        u32 o = shk[i];
        if (o == (u32)i) continue;
        bool mutual = (shk[o] == (u32)i);
        if (mutual && (u32)i < o) continue;
        scomp[i] = o;
        u64 cc = scand[i];
        u32 e = (u32)cc;
        u32 j = atomicAdd(&mstcnt[k], 1u);
        if (j < CAP) { mkey[k * CAP + j] = cc; mpay[k * CAP + j] = ep[(size_t)k * NE + e]; }
    }
    __syncthreads();
    for (int i = threadIdx.x; i < CAP; i += 1024) scomp[i] = rootofs(scomp, i);
    __syncthreads();
    for (int i = threadIdx.x; i < CAP; i += 1024) {
        comp_g[k * CAP + i] = scomp[i];
        cand_g[k * CAP + i] = ~0ull;
    }
}

// ---------------- sort MSF edges per filtration (bitonic in LDS) ---------------
__global__ void k_sort(const u32* mstcnt, u64* __restrict__ mkey, u32* __restrict__ mpay) {
    __shared__ u64 skey[CAP];   // 32 KB
    __shared__ u32 spay[CAP];   // 16 KB
    int k = blockIdx.x;
    u32 cnt = mstcnt[k]; if (cnt > CAP) cnt = CAP;
    for (int i = threadIdx.x; i < CAP; i += 256) {
        skey[i] = (i < (int)cnt) ? mkey[k * CAP + i] : ~0ull;
        spay[i] = (i < (int)cnt) ? mpay[k * CAP + i] : 0u;
    }
    __syncthreads();
    for (int sz = 2; sz <= CAP; sz <<= 1) {
        for (int st = sz >> 1; st >= 1; st >>= 1) {
            for (int i = threadIdx.x; i < CAP; i += 256) {
                int j = i ^ st;
                if (j > i) {
                    bool up = ((i & sz) == 0);
                    u64 a = skey[i], b = skey[j];
                    bool sw = up ? (a > b) : (a < b);
                    if (sw) {
                        skey[i] = b; skey[j] = a;
                        u32 tp = spay[i]; spay[i] = spay[j]; spay[j] = tp;
                    }
                }
            }
            __syncthreads();
        }
    }
    for (int i = threadIdx.x; i < CAP; i += 256) {
        mkey[k * CAP + i] = skey[i];
        mpay[k * CAP + i] = spay[i];
    }
}

// ---------------- elder-rule pairing (serial Kruskal over sorted MSF, in LDS) --
__device__ __forceinline__ u32 findp(u64* pf, u32 x) {
    u32 p = (u32)pf[x];
    while (p != x) {
        u32 g = (u32)pf[p];
        pf[x] = (pf[x] & 0xFFFFFFFF00000000ull) | g;  // path halving
        x = g;
        p = (u32)pf[x];
    }
    return x;
}

__global__ void k_pair(const u32* nmin, const u32* __restrict__ mlist, const u32* mstcnt,
                       const u64* __restrict__ mkey, const u32* __restrict__ mpay,
                       const float* __restrict__ f, float* __restrict__ dval) {
    __shared__ u64 pf[CAP];    // 32 KB
    __shared__ u32 skey[CAP];  // 16 KB
    __shared__ u32 spay[CAP];  // 16 KB
    int k = blockIdx.x;
    u32 nm = nmin[k]; if (nm > CAP) nm = CAP;
    u32 cnt = mstcnt[k]; if (cnt > CAP) cnt = CAP;
    for (int v = threadIdx.x; v < NV; v += 512) dval[k * NV + v] = f[k * NV + v];
    for (int i = threadIdx.x; i < CAP; i += 512) {
        float fm = 0.f;
        if (i < (int)nm) fm = f[k * NV + mlist[k * CAP + i]];
        pf[i] = ((u64)__float_as_uint(fm) << 32) | (u32)i;
        skey[i] = (u32)(mkey[k * CAP + i] >> 32);
        spay[i] = mpay[k * CAP + i];
    }
    __syncthreads();
    if (threadIdx.x == 0) {
        u32 wb = skey[0], pp = spay[0];
        for (u32 j = 0; j < cnt; j++) {
            u32 jn = (j + 1 < cnt) ? j + 1 : 0;
            u32 wb2 = skey[jn], pp2 = spay[jn];  // prefetch
            u32 A = findp(pf, pp >> 16);
            u32 B = findp(pf, pp & 0xFFFFu);
            if (A != B) {
                float fA = __uint_as_float((u32)(pf[A] >> 32));
                float fB = __uint_as_float((u32)(pf[B] >> 32));
                u32 old_, yg;
                if (fA <= fB) { old_ = A; yg = B; } else { old_ = B; yg = A; }
                pf[yg] = ((u64)wb << 32) | old_;  // high32 := death sortbits
            }
            wb = wb2; pp = pp2;
        }
    }
    __syncthreads();
    for (int i = threadIdx.x; i < (int)nm; i += 512) {
        if ((u32)pf[i] != (u32)i)
            dval[k * NV + mlist[k * CAP + i]] = isb((u32)(pf[i] >> 32));
    }
}

// ---------------- coordinate features -> bf16 directly into fused A ------------
__global__ void k_coordb(const float* __restrict__ f, const float* __restrict__ dval,
                         const float* __restrict__ tri_t, const float* __restrict__ gmu,
                         const float* __restrict__ gsig, const float* __restrict__ lw,
                         const float* __restrict__ rc, const float* __restrict__ rr,
                         u16* __restrict__ A) {
    int t = blockIdx.x * 256 + threadIdx.x;  // 160000
    int k = t / NV, v = t % NV;
    float b = f[t], d = dval[t];
    float o[12];
    float s = gsig[0];
    float inv2s2 = 1.0f / (2.0f * s * s);
    float r = fabsf(rr[0]);
#pragma unroll
    for (int j = 0; j < 3; j++) {
        float tri = d - fabsf(tri_t[j] - b);
        o[j] = tri > 0.f ? tri : 0.f;
        float dx = b - gmu[2 * j], dy = d - gmu[2 * j + 1];
        o[3 + j] = expf(-(dx * dx + dy * dy) * inv2s2);
        o[6 + j] = b * lw[2 * j] + d * lw[2 * j + 1];
        float q = fabsf(b - rc[2 * j]) + fabsf(d - rc[2 * j + 1]);
        o[9 + j] = 1.0f / (1.0f + q) - 1.0f / (1.0f + fabsf(r - q));
    }
    u16* dst = A + (size_t)v * KP + FIN + k * 12;  // 4B-aligned (2048+24k bytes)
    u32* d32 = (u32*)dst;
#pragma unroll
    for (int j = 0; j < 6; j++)
        d32[j] = (u32)f2bf(o[2 * j]) | ((u32)f2bf(o[2 * j + 1]) << 16);
}

// ---------------- GEMM2: out = A(bf16) @ W(bf16)^T + bias, MFMA ----------------
__global__ __launch_bounds__(256, 2) void k_gemm2(
    const u16* __restrict__ A, const u16* __restrict__ W,
    const float* __restrict__ bias, float* __restrict__ out) {
    __shared__ u16 As[128 * LDA];  // 18 KB
    __shared__ u16 Bs[128 * LDA];  // 18 KB
    int n0 = blockIdx.x * 128, m0 = blockIdx.y * 128;
    int t = threadIdx.x;
    int wave = t >> 6, lane = t & 63;
    int wm = (wave >> 1) * 64, wn = (wave & 1) * 64;
    int lrow = lane & 15, lq = lane >> 4;
    f32x4 acc[4][4];
#pragma unroll
    for (int i = 0; i < 4; i++)
#pragma unroll
        for (int j = 0; j < 4; j++) acc[i][j] = (f32x4){0.f, 0.f, 0.f, 0.f};

    int rowc[4], colc[4];
    uint4 av[4], bv[4];
#pragma unroll
    for (int i = 0; i < 4; i++) {
        int c = i * 256 + t;            // 0..1023 chunks of 8 bf16
        rowc[i] = c >> 3;
        colc[i] = (c & 7) * 8;
        av[i] = *(const uint4*)(A + (size_t)(m0 + rowc[i]) * KP + colc[i]);
        bv[i] = *(const uint4*)(W + (size_t)(n0 + rowc[i]) * KP + colc[i]);
    }
#pragma unroll 1
    for (int step = 0; step < KP / 64; step++) {
        __syncthreads();
#pragma unroll
        for (int i = 0; i < 4; i++) {
            *(uint4*)(As + rowc[i] * LDA + colc[i]) = av[i];
            *(uint4*)(Bs + rowc[i] * LDA + colc[i]) = bv[i];
        }
        __syncthreads();
        int k0n = (step + 1 < KP / 64) ? (step + 1) * 64 : 0;  // prefetch (clamped)
#pragma unroll
        for (int i = 0; i < 4; i++) {
            av[i] = *(const uint4*)(A + (size_t)(m0 + rowc[i]) * KP + k0n + colc[i]);
            bv[i] = *(const uint4*)(W + (size_t)(n0 + rowc[i]) * KP + k0n + colc[i]);
        }
#pragma unroll
        for (int kh = 0; kh < 2; kh++) {
            int kk = kh * 32 + lq * 8;
            bf16x8 af[4], bfr[4];
#pragma unroll
            for (int mt = 0; mt < 4; mt++)
                af[mt] = *(const bf16x8*)(As + (wm + mt * 16 + lrow) * LDA + kk);
#pragma unroll
            for (int nt = 0; nt < 4; nt++)
                bfr[nt] = *(const bf16x8*)(Bs + (wn + nt * 16 + lrow) * LDA + kk);
#pragma unroll
            for (int mt = 0; mt < 4; mt++)
#pragma unroll
                for (int nt = 0; nt < 4; nt++)
                    acc[mt][nt] = __builtin_amdgcn_mfma_f32_16x16x32_bf16(
                        af[mt], bfr[nt], acc[mt][nt], 0, 0, 0);
        }
    }
    // epilogue: row = (lane>>4)*4 + reg, col = lane&15  [verified C/D layout]
#pragma unroll
    for (int nt = 0; nt < 4; nt++) {
        int o = n0 + wn + nt * 16 + lrow;
        float bz = bias[o];
#pragma unroll
        for (int mt = 0; mt < 4; mt++) {
#pragma unroll
            for (int i = 0; i < 4; i++) {
                int v = m0 + wm + mt * 16 + lq * 4 + i;
                if (v < NV) out[(size_t)v * FOUT + o] = acc[mt][nt][i] + bz;
            }
        }
    }
}

extern "C" void kernel_launch(void* const* d_in, const int* in_sizes, int n_in,
                              void* d_out, int out_size, void* d_ws, size_t ws_size,
                              hipStream_t stream) {
    const float* x     = (const float*)d_in[0];
    const int*   ei    = (const int*)d_in[1];
    const float* fw    = (const float*)d_in[2];
    const float* fbv   = (const float*)d_in[3];
    const float* tri_t = (const float*)d_in[4];
    const float* gmu   = (const float*)d_in[5];
    const float* gsig  = (const float*)d_in[6];
    const float* lw    = (const float*)d_in[7];
    const float* rc    = (const float*)d_in[8];
    const float* rr    = (const float*)d_in[9];
    const float* ow    = (const float*)d_in[10];
    const float* ob    = (const float*)d_in[11];
    float* out = (float*)d_out;

    char* p = (char*)d_ws;
    auto alloc = [&](size_t bytes) -> void* {
        void* q = (void*)p;
        p += (bytes + 255) & ~(size_t)255;
        return q;
    };
    float* f     = (float*)alloc((size_t)NK * NV * 4);
    u64*   cd    = (u64*)  alloc((size_t)NK * NV * 8);
    u32*   basin = (u32*)  alloc((size_t)NK * NV * 4);
    u32*   dense = (u32*)  alloc((size_t)NK * NV * 4);
    u32*   mlist = (u32*)  alloc((size_t)NK * CAP * 4);
    u32*   cnts  = (u32*)  alloc(64 * 4);
    u64*   wkey  = (u64*)  alloc((size_t)NK * NE * 8);
    u32*   ep    = (u32*)  alloc((size_t)NK * NE * 4);
    u32*   comp  = (u32*)  alloc((size_t)NK * CAP * 4);
    u64*   cand  = (u64*)  alloc((size_t)NK * CAP * 8);
    u64*   mkey  = (u64*)  alloc((size_t)NK * CAP * 8);
    u32*   mpay  = (u32*)  alloc((size_t)NK * CAP * 4);
    float* dval  = (float*)alloc((size_t)NK * NV * 4);
    u16*   Ab    = (u16*)  alloc((size_t)MP * KP * 2);   // 46.3 MB fused [x|coord|pad]
    u16*   Wb    = (u16*)  alloc((size_t)FOUT * KP * 2); // 1.2 MB
    u32* nmin = cnts; u32* mstcnt = cnts + 8;

    k_init<<<128, 256, 0, stream>>>(comp, cand, cnts);
    k_f<<<5000, 256, 0, stream>>>(x, fw, fbv, f);
    k_castx<<<(MP * 144 + 255) / 256, 256, 0, stream>>>(x, Ab);
    k_castw<<<(FOUT * 144 + 255) / 256, 256, 0, stream>>>(ow, Wb);
    k_initdesc<<<625, 256, 0, stream>>>(f, cd);
    k_descedge<<<3125, 256, 0, stream>>>(ei, f, cd);
    k_basin<<<625, 256, 0, stream>>>(cd, basin);
    k_minima<<<625, 256, 0, stream>>>(cd, nmin, mlist, dense);
    k_edgeprep<<<3125, 256, 0, stream>>>(ei, f, basin, dense, wkey, ep);
    for (int r = 0; r < ROUNDS; r++) {
        k_candA<<<dim3(NB, NK), 256, 0, stream>>>(ep, wkey, comp, cand);
        k_round<<<NK, 1024, 0, stream>>>(cand, ep, comp, mstcnt, mkey, mpay);
    }
    k_sort<<<8, 256, 0, stream>>>(mstcnt, mkey, mpay);
    k_pair<<<8, 512, 0, stream>>>(nmin, mlist, mstcnt, mkey, mpay, f, dval);
    k_coordb<<<625, 256, 0, stream>>>(f, dval, tri_t, gmu, gsig, lw, rc, rr, Ab);
    k_gemm2<<<dim3(4, 157), 256, 0, stream>>>(Ab, Wb, ob, out);
}

// Round 4
// 1229.986 us; speedup vs baseline: 3.5194x; 1.1985x over previous
//
#include <hip/hip_runtime.h>
#include <stdint.h>

#define NV 20000
#define NE 100000
#define NK 8
#define FIN 1024
#define FOUT 512
#define FTOT 1120
#define KP 1152           // K padded to 18*64
#define MP 20096          // M padded to 157*128
#define CAP 4096
#define ROUNDS 13
#define NB 32             // edge-chunk blocks per filtration in k_candA
#define CHUNK (NE / NB)
#define LDA 72            // LDS row stride (bf16 elems): 64 + 8 pad

typedef unsigned int u32;
typedef unsigned long long u64;
typedef unsigned short u16;
typedef __attribute__((ext_vector_type(8))) short bf16x8;
typedef __attribute__((ext_vector_type(4))) float f32x4;

// float -> order-preserving unsigned bits, and inverse
__device__ __forceinline__ u32 sb(float x) {
    u32 u = __float_as_uint(x);
    return u ^ ((u & 0x80000000u) ? 0xFFFFFFFFu : 0x80000000u);
}
__device__ __forceinline__ float isb(u32 s) {
    u32 u = (s & 0x80000000u) ? (s ^ 0x80000000u) : ~s;
    return __uint_as_float(u);
}
// float -> bf16 (RNE)
__device__ __forceinline__ u16 f2bf(float f) {
    u32 u = __float_as_uint(f);
    return (u16)((u + 0x7FFFu + ((u >> 16) & 1u)) >> 16);
}

// ---------------- GEMM1: f[k][v] = x[v] . filt_w[k] + filt_b[k] (fp32 exact path)
__global__ void k_f(const float* __restrict__ x, const float* __restrict__ fw,
                    const float* __restrict__ fb, float* __restrict__ f) {
    __shared__ float w[NK * FIN];  // 32 KB
    for (int i = threadIdx.x; i < NK * FIN; i += 256) w[i] = fw[i];
    __syncthreads();
    int wave = threadIdx.x >> 6, lane = threadIdx.x & 63;
    int v = blockIdx.x * 4 + wave;  // 5000 * 4 waves = 20000 exact
    float acc[NK];
#pragma unroll
    for (int k = 0; k < NK; k++) acc[k] = 0.f;
    const float* xr = x + (size_t)v * FIN;
    for (int c = 0; c < FIN / 64; c++) {
        int i = c * 64 + lane;
        float xv = xr[i];
#pragma unroll
        for (int k = 0; k < NK; k++) acc[k] = fmaf(xv, w[k * FIN + i], acc[k]);
    }
#pragma unroll
    for (int off = 32; off >= 1; off >>= 1)
#pragma unroll
        for (int k = 0; k < NK; k++) acc[k] += __shfl_xor(acc[k], off, 64);
    if (lane < NK) f[lane * NV + v] = acc[lane] + fb[lane];
}

// ---------------- init: comp identity, cand = ~0, counters = 0 ----------------
__global__ void k_init(u32* __restrict__ comp, u64* __restrict__ cand, u32* cnts) {
    int t = blockIdx.x * 256 + threadIdx.x;  // 32768
    comp[t] = (u32)(t % CAP);
    cand[t] = ~0ull;
    if (t < 16) cnts[t] = 0;
}

// ---------------- cast x into fused bf16 A (cols 0..1023; zero pads) ----------
__global__ void k_castx(const float* __restrict__ x, u16* __restrict__ A) {
    int t = blockIdx.x * 256 + threadIdx.x;  // MP * 144
    if (t >= MP * 144) return;
    int v = t / 144, c = (t % 144) * 8;
    u32 pk[4];
    if (v < NV && c < FIN) {
        const float* xr = x + (size_t)v * FIN + c;
#pragma unroll
        for (int j = 0; j < 4; j++)
            pk[j] = (u32)f2bf(xr[2 * j]) | ((u32)f2bf(xr[2 * j + 1]) << 16);
    } else {
#pragma unroll
        for (int j = 0; j < 4; j++) pk[j] = 0u;
    }
    *(uint4*)(A + (size_t)v * KP + c) = make_uint4(pk[0], pk[1], pk[2], pk[3]);
}

// ---------------- cast out_w into bf16 W [512][1152] --------------------------
__global__ void k_castw(const float* __restrict__ ow, u16* __restrict__ W) {
    int t = blockIdx.x * 256 + threadIdx.x;  // 512*144
    if (t >= FOUT * 144) return;
    int n = t / 144, c = (t % 144) * 8;
    u32 pk[4];
    if (c < FTOT) {
        const float* wr = ow + (size_t)n * FTOT + c;
#pragma unroll
        for (int j = 0; j < 4; j++)
            pk[j] = (u32)f2bf(wr[2 * j]) | ((u32)f2bf(wr[2 * j + 1]) << 16);
    } else {
#pragma unroll
        for (int j = 0; j < 4; j++) pk[j] = 0u;
    }
    *(uint4*)(W + (size_t)n * KP + c) = make_uint4(pk[0], pk[1], pk[2], pk[3]);
}

// ---------------- descent pointers ----------------
__global__ void k_initdesc(const float* __restrict__ f, u64* __restrict__ cd) {
    int t = blockIdx.x * 256 + threadIdx.x;  // 160000
    u32 v = (u32)(t % NV);
    cd[t] = ((u64)sb(f[t]) << 32) | v;
}

__global__ void k_descedge(const int* __restrict__ ei, const float* __restrict__ f,
                           u64* __restrict__ cd) {
    int t = blockIdx.x * 256 + threadIdx.x;  // 800000
    int k = t / NE, e = t % NE;
    int a = ei[e], b = ei[NE + e];
    if (a == b) return;
    float fa = f[k * NV + a], fb2 = f[k * NV + b];
    int d, l; float fl;
    if (fa >= fb2) { d = a; l = b; fl = fb2; } else { d = b; l = a; fl = fa; }
    u64 key = ((u64)sb(fl) << 32) | (u32)l;
    atomicMin(&cd[k * NV + d], key);
}

__global__ void k_basin(const u64* __restrict__ cd, u32* __restrict__ basin) {
    int t = blockIdx.x * 256 + threadIdx.x;
    int k = t / NV;
    u32 m = (u32)(t % NV);
    const u64* c = cd + (size_t)k * NV;
    while (true) { u32 n = (u32)c[m]; if (n == m) break; m = n; }
    basin[t] = m;
}

__global__ void k_minima(const u64* __restrict__ cd, u32* nmin,
                         u32* __restrict__ mlist, u32* __restrict__ dense) {
    int t = blockIdx.x * 256 + threadIdx.x;
    int k = t / NV; u32 v = (u32)(t % NV);
    if ((u32)cd[t] == v) {
        u32 i = atomicAdd(&nmin[k], 1u);
        if (i < CAP) { mlist[k * CAP + i] = v; dense[t] = i; }
    }
}

__global__ void k_edgeprep(const int* __restrict__ ei, const float* __restrict__ f,
                           const u32* __restrict__ basin, const u32* __restrict__ dense,
                           u64* __restrict__ wkey, u32* __restrict__ ep) {
    int t = blockIdx.x * 256 + threadIdx.x;  // 800000
    int k = t / NE, e = t % NE;
    int a = ei[e], b = ei[NE + e];
    if (a == b) { ep[t] = 0xFFFFFFFFu; return; }
    float fa = f[k * NV + a], fb2 = f[k * NV + b];
    float w = (fa >= fb2) ? fa : fb2;
    wkey[t] = ((u64)sb(w) << 32) | (u32)e;
    u32 ba = basin[k * NV + a], bb = basin[k * NV + b];
    if (ba == bb) { ep[t] = 0xFFFFFFFFu; return; }
    u32 da = dense[k * NV + ba], db = dense[k * NV + bb];
    ep[t] = (da << 16) | db;
}

// ---------------- Boruvka phase A: per-block LDS cand, sparse flush ------------
__device__ __forceinline__ u32 rootofs(const u32* c, u32 i) {
    while (true) { u32 p = c[i]; if (p == i) return i; i = p; }
}

__global__ void k_candA(const u32* __restrict__ ep, const u64* __restrict__ wkey,
                        const u32* __restrict__ comp_g, u64* __restrict__ cand_g) {
    __shared__ u32 scomp[CAP];  // 16 KB
    __shared__ u64 scand[CAP];  // 32 KB
    int k = blockIdx.y, b = blockIdx.x;
    for (int i = threadIdx.x; i < CAP; i += 256) {
        scomp[i] = comp_g[k * CAP + i];
        scand[i] = ~0ull;
    }
    __syncthreads();
    int e0 = b * CHUNK;
    const u32* epk = ep + (size_t)k * NE;
    const u64* wkk = wkey + (size_t)k * NE;
    for (int e = e0 + threadIdx.x; e < e0 + CHUNK; e += 256) {
        u32 p32 = epk[e];
        if (p32 == 0xFFFFFFFFu) continue;
        u32 A = rootofs(scomp, p32 >> 16), B = rootofs(scomp, p32 & 0xFFFFu);
        if (A == B) continue;
        u64 w = wkk[e];
        atomicMin(&scand[A], w);
        atomicMin(&scand[B], w);
    }
    __syncthreads();
    u64* cnd = cand_g + (size_t)k * CAP;
    for (int i = threadIdx.x; i < CAP; i += 256) {
        u64 v = scand[i];
        if (v != ~0ull) atomicMin(&cnd[i], v);
    }
}

// ---------------- Boruvka phase B: hook + apply + compress + clear (fused) -----
__global__ void k_round(u64* __restrict__ cand_g, const u32* __restrict__ ep,
                        u32* __restrict__ comp_g, u32* mstcnt,
                        u64* __restrict__ mkey, u32* __restrict__ mpay) {
    __shared__ u64 scand[CAP];  // 32 KB
    __shared__ u32 scomp[CAP];  // 16 KB
    __shared__ u32 shk[CAP];    // 16 KB
    int k = blockIdx.x;
    for (int i = threadIdx.x; i < CAP; i += 1024) {
        scand[i] = cand_g[k * CAP + i];
        scomp[i] = comp_g[k * CAP + i];
    }
    __syncthreads();
    for (int i = threadIdx.x; i < CAP; i += 1024) {
        u64 cc = scand[i];
        if (cc == ~0ull) { shk[i] = (u32)i; continue; }
        u32 e = (u32)cc;
        u32 p32 = ep[(size_t)k * NE + e];
        u32 A = rootofs(scomp, p32 >> 16), B = rootofs(scomp, p32 & 0xFFFFu);
        shk[i] = (A == (u32)i) ? B : A;
    }
    __syncthreads();
    for (int i = threadIdx.x; i < CAP; i += 1024) {
        u32 o = shk[i];
        if (o == (u32)i) continue;
        bool mutual = (shk[o] == (u32)i);
        if (mutual && (u32)i < o) continue;
        scomp[i] = o;
        u64 cc = scand[i];
        u32 e = (u32)cc;
        u32 j = atomicAdd(&mstcnt[k], 1u);
        if (j < CAP) { mkey[k * CAP + j] = cc; mpay[k * CAP + j] = ep[(size_t)k * NE + e]; }
    }
    __syncthreads();
    for (int i = threadIdx.x; i < CAP; i += 1024) scomp[i] = rootofs(scomp, i);
    __syncthreads();
    for (int i = threadIdx.x; i < CAP; i += 1024) {
        comp_g[k * CAP + i] = scomp[i];
        cand_g[k * CAP + i] = ~0ull;
    }
}

// ---------------- sort MSF edges per filtration (bitonic in LDS) ---------------
__global__ void k_sort(const u32* mstcnt, u64* __restrict__ mkey, u32* __restrict__ mpay) {
    __shared__ u64 skey[CAP];   // 32 KB
    __shared__ u32 spay[CAP];   // 16 KB
    int k = blockIdx.x;
    u32 cnt = mstcnt[k]; if (cnt > CAP) cnt = CAP;
    for (int i = threadIdx.x; i < CAP; i += 256) {
        skey[i] = (i < (int)cnt) ? mkey[k * CAP + i] : ~0ull;
        spay[i] = (i < (int)cnt) ? mpay[k * CAP + i] : 0u;
    }
    __syncthreads();
    for (int sz = 2; sz <= CAP; sz <<= 1) {
        for (int st = sz >> 1; st >= 1; st >>= 1) {
            for (int i = threadIdx.x; i < CAP; i += 256) {
                int j = i ^ st;
                if (j > i) {
                    bool up = ((i & sz) == 0);
                    u64 a = skey[i], b = skey[j];
                    bool sw = up ? (a > b) : (a < b);
                    if (sw) {
                        skey[i] = b; skey[j] = a;
                        u32 tp = spay[i]; spay[i] = spay[j]; spay[j] = tp;
                    }
                }
            }
            __syncthreads();
        }
    }
    for (int i = threadIdx.x; i < CAP; i += 256) {
        mkey[k * CAP + i] = skey[i];
        mpay[k * CAP + i] = spay[i];
    }
}

// ---------------- dval default: death = birth ---------------------------------
__global__ void k_dvinit(const float* __restrict__ f, float* __restrict__ dval) {
    int t = blockIdx.x * 256 + threadIdx.x;  // 160000
    dval[t] = f[t];
}

// ---- elder-rule pairing: wave-parallel speculative Kruskal windows (64 edges) --
// par[i]: parent (dense id). val[i]: f bits while root; death sortbits once dead.
// One wave per filtration. Sequential semantics preserved exactly:
//   - every sorted MSF edge merges two distinct components (forest edges)
//   - within a window, merge chains ascend in lane index, so one ascending
//     shuffle pass applies any earlier-lane remap chain; fixed-point iterate
//     (lane i provably final after <= i+1 passes; ballot early-exit).
__global__ __launch_bounds__(64) void k_pairw(
    const u32* nmin, const u32* __restrict__ mlist, const u32* mstcnt,
    const u64* __restrict__ mkey, const u32* __restrict__ mpay,
    const float* __restrict__ f, float* __restrict__ dval) {
    __shared__ u32 par[CAP];  // 16 KB
    __shared__ u32 val[CAP];  // 16 KB
    int k = blockIdx.x;
    int lane = threadIdx.x;
    u32 nm = nmin[k]; if (nm > CAP) nm = CAP;
    u32 cnt = mstcnt[k]; if (cnt > CAP) cnt = CAP;
    for (int i = lane; i < CAP; i += 64) {
        par[i] = (u32)i;
        val[i] = (i < (int)nm) ? __float_as_uint(f[k * NV + mlist[k * CAP + i]]) : 0u;
    }
    __syncthreads();
    u32 nw = (cnt + 63) >> 6;
    for (u32 w = 0; w < nw; w++) {
        u32 j = w * 64 + (u32)lane;
        bool valid = j < cnt;
        u32 wb = 0, la = 0, lb = 0;
        if (valid) {
            u64 key = mkey[(size_t)k * CAP + j];
            wb = (u32)(key >> 32);
            u32 pay = mpay[(size_t)k * CAP + j];
            la = pay >> 16; lb = pay & 0xFFFFu;
        }
        // phase A: pre-window roots with path halving (parallel across lanes)
        u32 rA = la, rB = lb;
        if (valid) {
            while (true) { u32 p = par[rA]; if (p == rA) break;
                           u32 g = par[p]; par[rA] = g; rA = (g == p) ? p : g; }
            while (true) { u32 p = par[rB]; if (p == rB) break;
                           u32 g = par[p]; par[rB] = g; rB = (g == p) ? p : g; }
        }
        u32 vA = valid ? val[rA] : 0u;
        u32 vB = valid ? val[rB] : 0u;
        // initial tentative merge (no in-window remaps)
        u32 fy = 0xFFFFFFFFu, fo = 0u, fvo = 0u;
        if (valid) {
            if (__uint_as_float(vA) <= __uint_as_float(vB)) { fo = rA; fvo = vA; fy = rB; }
            else                                            { fo = rB; fvo = vB; fy = rA; }
        }
        // phase B: fixed-point over earlier-lane merges (registers + shuffles)
        for (int it = 0; it < 64; it++) {
            u32 cA = rA, cvA = vA, cB = rB, cvB = vB;
#pragma unroll 8
            for (int jj = 0; jj < 64; jj++) {
                u32 oy = __shfl(fy, jj);
                u32 oo = __shfl(fo, jj);
                u32 ov = __shfl(fvo, jj);
                bool app = (jj < lane);
                if (app && cA == oy) { cA = oo; cvA = ov; }
                if (app && cB == oy) { cB = oo; cvB = ov; }
            }
            u32 ny, no, nvo;
            if (__uint_as_float(cvA) <= __uint_as_float(cvB)) { no = cA; nvo = cvA; ny = cB; }
            else                                              { no = cB; nvo = cvB; ny = cA; }
            bool ch = valid && (ny != fy || no != fo);
            if (valid) { fy = ny; fo = no; fvo = nvo; }
            if (!__any(ch)) break;
        }
        // commit: distinct fy across lanes; chains remain chaseable
        if (valid) { par[fy] = fo; val[fy] = wb; }
        __syncthreads();
    }
    // extraction: dead minima get death value from val slot
    for (int i = lane; i < (int)nm; i += 64) {
        if (par[i] != (u32)i)
            dval[k * NV + mlist[k * CAP + i]] = isb(val[i]);
    }
}

// ---------------- coordinate features -> bf16 directly into fused A ------------
__global__ void k_coordb(const float* __restrict__ f, const float* __restrict__ dval,
                         const float* __restrict__ tri_t, const float* __restrict__ gmu,
                         const float* __restrict__ gsig, const float* __restrict__ lw,
                         const float* __restrict__ rc, const float* __restrict__ rr,
                         u16* __restrict__ A) {
    int t = blockIdx.x * 256 + threadIdx.x;  // 160000
    int k = t / NV, v = t % NV;
    float b = f[t], d = dval[t];
    float o[12];
    float s = gsig[0];
    float inv2s2 = 1.0f / (2.0f * s * s);
    float r = fabsf(rr[0]);
#pragma unroll
    for (int j = 0; j < 3; j++) {
        float tri = d - fabsf(tri_t[j] - b);
        o[j] = tri > 0.f ? tri : 0.f;
        float dx = b - gmu[2 * j], dy = d - gmu[2 * j + 1];
        o[3 + j] = expf(-(dx * dx + dy * dy) * inv2s2);
        o[6 + j] = b * lw[2 * j] + d * lw[2 * j + 1];
        float q = fabsf(b - rc[2 * j]) + fabsf(d - rc[2 * j + 1]);
        o[9 + j] = 1.0f / (1.0f + q) - 1.0f / (1.0f + fabsf(r - q));
    }
    u16* dst = A + (size_t)v * KP + FIN + k * 12;  // 4B-aligned (2048+24k bytes)
    u32* d32 = (u32*)dst;
#pragma unroll
    for (int j = 0; j < 6; j++)
        d32[j] = (u32)f2bf(o[2 * j]) | ((u32)f2bf(o[2 * j + 1]) << 16);
}

// ---------------- GEMM2: out = A(bf16) @ W(bf16)^T + bias, MFMA ----------------
__global__ __launch_bounds__(256, 2) void k_gemm2(
    const u16* __restrict__ A, const u16* __restrict__ W,
    const float* __restrict__ bias, float* __restrict__ out) {
    __shared__ u16 As[128 * LDA];  // 18 KB
    __shared__ u16 Bs[128 * LDA];  // 18 KB
    int n0 = blockIdx.x * 128, m0 = blockIdx.y * 128;
    int t = threadIdx.x;
    int wave = t >> 6, lane = t & 63;
    int wm = (wave >> 1) * 64, wn = (wave & 1) * 64;
    int lrow = lane & 15, lq = lane >> 4;
    f32x4 acc[4][4];
#pragma unroll
    for (int i = 0; i < 4; i++)
#pragma unroll
        for (int j = 0; j < 4; j++) acc[i][j] = (f32x4){0.f, 0.f, 0.f, 0.f};

    int rowc[4], colc[4];
    uint4 av[4], bv[4];
#pragma unroll
    for (int i = 0; i < 4; i++) {
        int c = i * 256 + t;            // 0..1023 chunks of 8 bf16
        rowc[i] = c >> 3;
        colc[i] = (c & 7) * 8;
        av[i] = *(const uint4*)(A + (size_t)(m0 + rowc[i]) * KP + colc[i]);
        bv[i] = *(const uint4*)(W + (size_t)(n0 + rowc[i]) * KP + colc[i]);
    }
#pragma unroll 1
    for (int step = 0; step < KP / 64; step++) {
        __syncthreads();
#pragma unroll
        for (int i = 0; i < 4; i++) {
            *(uint4*)(As + rowc[i] * LDA + colc[i]) = av[i];
            *(uint4*)(Bs + rowc[i] * LDA + colc[i]) = bv[i];
        }
        __syncthreads();
        int k0n = (step + 1 < KP / 64) ? (step + 1) * 64 : 0;  // prefetch (clamped)
#pragma unroll
        for (int i = 0; i < 4; i++) {
            av[i] = *(const uint4*)(A + (size_t)(m0 + rowc[i]) * KP + k0n + colc[i]);
            bv[i] = *(const uint4*)(W + (size_t)(n0 + rowc[i]) * KP + k0n + colc[i]);
        }
#pragma unroll
        for (int kh = 0; kh < 2; kh++) {
            int kk = kh * 32 + lq * 8;
            bf16x8 af[4], bfr[4];
#pragma unroll
            for (int mt = 0; mt < 4; mt++)
                af[mt] = *(const bf16x8*)(As + (wm + mt * 16 + lrow) * LDA + kk);
#pragma unroll
            for (int nt = 0; nt < 4; nt++)
                bfr[nt] = *(const bf16x8*)(Bs + (wn + nt * 16 + lrow) * LDA + kk);
#pragma unroll
            for (int mt = 0; mt < 4; mt++)
#pragma unroll
                for (int nt = 0; nt < 4; nt++)
                    acc[mt][nt] = __builtin_amdgcn_mfma_f32_16x16x32_bf16(
                        af[mt], bfr[nt], acc[mt][nt], 0, 0, 0);
        }
    }
    // epilogue: row = (lane>>4)*4 + reg, col = lane&15  [verified C/D layout]
#pragma unroll
    for (int nt = 0; nt < 4; nt++) {
        int o = n0 + wn + nt * 16 + lrow;
        float bz = bias[o];
#pragma unroll
        for (int mt = 0; mt < 4; mt++) {
#pragma unroll
            for (int i = 0; i < 4; i++) {
                int v = m0 + wm + mt * 16 + lq * 4 + i;
                if (v < NV) out[(size_t)v * FOUT + o] = acc[mt][nt][i] + bz;
            }
        }
    }
}

extern "C" void kernel_launch(void* const* d_in, const int* in_sizes, int n_in,
                              void* d_out, int out_size, void* d_ws, size_t ws_size,
                              hipStream_t stream) {
    const float* x     = (const float*)d_in[0];
    const int*   ei    = (const int*)d_in[1];
    const float* fw    = (const float*)d_in[2];
    const float* fbv   = (const float*)d_in[3];
    const float* tri_t = (const float*)d_in[4];
    const float* gmu   = (const float*)d_in[5];
    const float* gsig  = (const float*)d_in[6];
    const float* lw    = (const float*)d_in[7];
    const float* rc    = (const float*)d_in[8];
    const float* rr    = (const float*)d_in[9];
    const float* ow    = (const float*)d_in[10];
    const float* ob    = (const float*)d_in[11];
    float* out = (float*)d_out;

    char* p = (char*)d_ws;
    auto alloc = [&](size_t bytes) -> void* {
        void* q = (void*)p;
        p += (bytes + 255) & ~(size_t)255;
        return q;
    };
    float* f     = (float*)alloc((size_t)NK * NV * 4);
    u64*   cd    = (u64*)  alloc((size_t)NK * NV * 8);
    u32*   basin = (u32*)  alloc((size_t)NK * NV * 4);
    u32*   dense = (u32*)  alloc((size_t)NK * NV * 4);
    u32*   mlist = (u32*)  alloc((size_t)NK * CAP * 4);
    u32*   cnts  = (u32*)  alloc(64 * 4);
    u64*   wkey  = (u64*)  alloc((size_t)NK * NE * 8);
    u32*   ep    = (u32*)  alloc((size_t)NK * NE * 4);
    u32*   comp  = (u32*)  alloc((size_t)NK * CAP * 4);
    u64*   cand  = (u64*)  alloc((size_t)NK * CAP * 8);
    u64*   mkey  = (u64*)  alloc((size_t)NK * CAP * 8);
    u32*   mpay  = (u32*)  alloc((size_t)NK * CAP * 4);
    float* dval  = (float*)alloc((size_t)NK * NV * 4);
    u16*   Ab    = (u16*)  alloc((size_t)MP * KP * 2);   // 46.3 MB fused [x|coord|pad]
    u16*   Wb    = (u16*)  alloc((size_t)FOUT * KP * 2); // 1.2 MB
    u32* nmin = cnts; u32* mstcnt = cnts + 8;

    k_init<<<128, 256, 0, stream>>>(comp, cand, cnts);
    k_f<<<5000, 256, 0, stream>>>(x, fw, fbv, f);
    k_dvinit<<<625, 256, 0, stream>>>(f, dval);
    k_castx<<<(MP * 144 + 255) / 256, 256, 0, stream>>>(x, Ab);
    k_castw<<<(FOUT * 144 + 255) / 256, 256, 0, stream>>>(ow, Wb);
    k_initdesc<<<625, 256, 0, stream>>>(f, cd);
    k_descedge<<<3125, 256, 0, stream>>>(ei, f, cd);
    k_basin<<<625, 256, 0, stream>>>(cd, basin);
    k_minima<<<625, 256, 0, stream>>>(cd, nmin, mlist, dense);
    k_edgeprep<<<3125, 256, 0, stream>>>(ei, f, basin, dense, wkey, ep);
    for (int r = 0; r < ROUNDS; r++) {
        k_candA<<<dim3(NB, NK), 256, 0, stream>>>(ep, wkey, comp, cand);
        k_round<<<NK, 1024, 0, stream>>>(cand, ep, comp, mstcnt, mkey, mpay);
    }
    k_sort<<<8, 256, 0, stream>>>(mstcnt, mkey, mpay);
    k_pairw<<<8, 64, 0, stream>>>(nmin, mlist, mstcnt, mkey, mpay, f, dval);
    k_coordb<<<625, 256, 0, stream>>>(f, dval, tri_t, gmu, gsig, lw, rc, rr, Ab);
    k_gemm2<<<dim3(4, 157), 256, 0, stream>>>(Ab, Wb, ob, out);
}